// Round 18
// baseline (77.553 us; speedup 1.0000x reference)
//
#include <hip/hip_runtime.h>
#include <hip/hip_bf16.h>

// SpiralDeblock: B=8, N_IN=7056, N_UP=28224, SEQ=9, CIN=64, COUT=32
namespace {
constexpr int kB    = 8;
constexpr int kNIn  = 7056;
constexpr int kNUp  = 28224;
constexpr int kSeq  = 9;
constexpr int kCout = 32;
constexpr int kCin  = 64;
constexpr int kE    = 3 * kNUp;          // 84672
constexpr int kNTiles = kNUp / 16;       // 1764 (exact)
constexpr int kWFragN = 18 * 2 * 64 * 8; // 18432 bf16 values (36,864 B)
constexpr int kCap   = 24;               // bucket capacity

// ws layout (bytes), 16B-aligned. poolb is TRANSPOSED: [r][b][c] bf16,
// row r = 1KB contiguous (8 batches x 128B) so one gemm fetch serves all b.
constexpr size_t kOffPool   = 0;                          // 28224*1024 = 28,901,376
constexpr size_t kOffWfrag  = 28901376;                   // 36,864
constexpr size_t kOffCur    = kOffWfrag + 36864;          // 112,896
constexpr size_t kOffBucket = kOffCur + 112896;           // N_UP*24*8 = 5,419,008
}

typedef __attribute__((ext_vector_type(8))) short short8;
typedef __attribute__((ext_vector_type(4))) float f32x4;

__device__ __forceinline__ unsigned short f32_to_bf16(float f) {  // RNE
    unsigned int u = __float_as_uint(f);
    u += 0x7fffu + ((u >> 16) & 1u);
    return (unsigned short)(u >> 16);
}

// --- zero cursor ------------------------------------------------------------
__global__ __launch_bounds__(256) void zero_kernel(int* __restrict__ cursor) {
    int i = blockIdx.x * 256 + threadIdx.x;
    if (i < kNUp) cursor[i] = 0;
}

// --- merged prep: blocks [0,72) W->fragment transpose; rest bucket edges ----
__global__ __launch_bounds__(256) void prep_kernel(const float* __restrict__ W,
                                                   unsigned short* __restrict__ wfrag,
                                                   const int* __restrict__ row,
                                                   const int* __restrict__ col,
                                                   const float* __restrict__ val,
                                                   int* __restrict__ cursor,
                                                   uint2* __restrict__ bucket) {
    int bid = blockIdx.x;
    if (bid < kWFragN / 256) {
        int i  = bid * 256 + threadIdx.x;
        int j  = i & 7;
        int l  = (i >> 3) & 63;
        int ct = (i >> 9) & 1;
        int ks = i >> 10;                            // 0..17
        int k  = ks * 32 + (l >> 4) * 8 + j;
        int o  = ct * 16 + (l & 15);
        wfrag[i] = f32_to_bf16(W[k * kCout + o]);
    } else {
        int e = (bid - kWFragN / 256) * 256 + threadIdx.x;
        if (e >= kE) return;
        int r = row[e];
        int slot = atomicAdd(&cursor[r], 1);
        if ((unsigned)slot < (unsigned)kCap)
            bucket[(size_t)r * kCap + slot] = make_uint2((unsigned)col[e], __float_as_uint(val[e]));
    }
}

// --- pool: pooled[r][b][c] = sum_edges x[b,col,c]*val (TRANSPOSED store) ----
// b = blockIdx&7: batch<->XCD affinity for the x reads (unchanged, 22.2 us).
__global__ __launch_bounds__(256) void pool_gather(const float* __restrict__ x,
                                                   const int* __restrict__ cursor,
                                                   const uint2* __restrict__ bucket,
                                                   unsigned short* __restrict__ poolb) {
    int t  = threadIdx.x;
    int c4 = t & 15;
    int b  = blockIdx.x & 7;
    int rb = blockIdx.x >> 3;
    int r  = rb * 16 + (t >> 4);
    int n  = min(cursor[r], kCap);
    const uint2* bk = bucket + (size_t)r * kCap;
    const float* xb = x + (size_t)b * kNIn * kCin + (size_t)c4 * 4;

    f32x4 acc = {0.f, 0.f, 0.f, 0.f};
#pragma unroll
    for (int p = 0; p < 4; ++p) {
        if (2 * p < n) {
            uint4 q = *reinterpret_cast<const uint4*>(bk + 2 * p);
            unsigned c0 = min(q.x, (unsigned)(kNIn - 1));
            float    v0 = __uint_as_float(q.y);
            unsigned c1 = min(q.z, (unsigned)(kNIn - 1));
            float    v1 = (2 * p + 1 < n) ? __uint_as_float(q.w) : 0.f;
            f32x4 xv0 = *reinterpret_cast<const f32x4*>(xb + (size_t)c0 * kCin);
            f32x4 xv1 = *reinterpret_cast<const f32x4*>(xb + (size_t)c1 * kCin);
#pragma unroll
            for (int j = 0; j < 4; ++j)
                acc[j] = fmaf(xv1[j], v1, fmaf(xv0[j], v0, acc[j]));
        }
    }
    for (int k = 8; k < n; ++k) {                    // rare tail
        uint2 ev = bk[k];
        float v = __uint_as_float(ev.y);
        f32x4 xv = *reinterpret_cast<const f32x4*>(xb + (size_t)ev.x * kCin);
#pragma unroll
        for (int j = 0; j < 4; ++j) acc[j] = fmaf(xv[j], v, acc[j]);
    }
    ushort4 o;
    o.x = f32_to_bf16(acc[0]);
    o.y = f32_to_bf16(acc[1]);
    o.z = f32_to_bf16(acc[2]);
    o.w = f32_to_bf16(acc[3]);
    // transposed: [r][b][c]
    *reinterpret_cast<ushort4*>(poolb + ((size_t)r * 8 + b) * 64 + c4 * 4) = o;
}

// --- MFMA GEMM v4: batch-fused, LDS-staged streaming A ----------------------
// r15-r17 evidence: gemm is scattered-gather-throughput bound (immune to
// ILP/MLP/occupancy). Fix: block = one 16-row n-tile x ALL 8 batches (indices
// are batch-independent). Per s: stage the 16 needed pooled rows (1KB each,
// fully contiguous, each serving 8 batches) into LDS double-buffer; 4 waves
// each compute 2 batches from LDS. VMEM: 16 contiguous 1KB loads per s per
// block vs 256 scattered 64B requests before (8M -> 2M segments device-wide).
// XOR-swizzle (m&7) on ds_write/read pair; global stays linear (rule #21).
__global__ __launch_bounds__(256) void gemm_mfma(const unsigned short* __restrict__ poolb,
                                                 const unsigned short* __restrict__ wfrag,
                                                 const float* __restrict__ bias,
                                                 const int* __restrict__ indices,
                                                 float* __restrict__ out) {
    __shared__ short8 Bs[10 * 2 * 64];               // 20,480 B (split-K window)
    __shared__ short8 As[2][16 * 64];                // 2 x 16KB A double-buffer
    int t = threadIdx.x;
    int l = t & 63, w = t >> 6, m = l & 15, kg = l >> 4;
    int ntile = blockIdx.x;
    const short8* wf = (const short8*)wfrag;

    int idxs[kSeq];
#pragma unroll
    for (int s = 0; s < kSeq; ++s) idxs[s] = indices[(ntile * 16 + m) * kSeq + s];

    int b0 = 2 * w, b1 = 2 * w + 1;
    float bsv0 = bias[m];
    float bsv1 = bias[16 + m];

    // prologue: stage s=0 rows (wave w stages tile-rows 4w..4w+3)
    {
        short8 pf[4];
#pragma unroll
        for (int i = 0; i < 4; ++i) {
            int rm = 4 * w + i;
            int rowid = __shfl(idxs[0], rm);         // wave-uniform row id
            pf[i] = *(const short8*)(poolb + (size_t)rowid * 512 + l * 8);
        }
#pragma unroll
        for (int i = 0; i < 4; ++i) {
            int rm = 4 * w + i;
            As[0][rm * 64 + (l ^ (rm & 7))] = pf[i]; // swizzled write
        }
    }
    // Bs phase 1: ks 0..9
#pragma unroll
    for (int i = 0; i < 5; ++i) Bs[i * 256 + t] = wf[i * 256 + t];
    __syncthreads();

    f32x4 accA0 = {0.f, 0.f, 0.f, 0.f}, accA1 = {0.f, 0.f, 0.f, 0.f};  // batch b0
    f32x4 accB0 = {0.f, 0.f, 0.f, 0.f}, accB1 = {0.f, 0.f, 0.f, 0.f};  // batch b1

#pragma unroll
    for (int s = 0; s < kSeq; ++s) {
        if (s == 5) {                                // Bs phase 2: ks 10..17
#pragma unroll
            for (int i = 0; i < 4; ++i) Bs[i * 256 + t] = wf[1280 + i * 256 + t];
            __syncthreads();
        }
        short8 pf[4];
        if (s < kSeq - 1) {                          // prefetch s+1 rows (global, contiguous)
#pragma unroll
            for (int i = 0; i < 4; ++i) {
                int rm = 4 * w + i;
                int rowid = __shfl(idxs[s + 1], rm);
                pf[i] = *(const short8*)(poolb + (size_t)rowid * 512 + l * 8);
            }
        }

        int sl = (s < 5) ? s : (s - 5);              // Bs phase-local slot
        short8 w00 = Bs[(4 * sl + 0) * 64 + l];
        short8 w01 = Bs[(4 * sl + 1) * 64 + l];
        short8 w10 = Bs[(4 * sl + 2) * 64 + l];
        short8 w11 = Bs[(4 * sl + 3) * 64 + l];

        const short8* Ab = &As[s & 1][0];
        int mswz = m & 7;
        short8 a0 = Ab[m * 64 + ((b0 * 8 + kg) ^ mswz)];       // b0, ch 0..31
        short8 a1 = Ab[m * 64 + ((b0 * 8 + 4 + kg) ^ mswz)];   // b0, ch 32..63
        short8 c0 = Ab[m * 64 + ((b1 * 8 + kg) ^ mswz)];       // b1, ch 0..31
        short8 c1 = Ab[m * 64 + ((b1 * 8 + 4 + kg) ^ mswz)];   // b1, ch 32..63

        accA0 = __builtin_amdgcn_mfma_f32_16x16x32_bf16(a0, w00, accA0, 0, 0, 0);
        accA1 = __builtin_amdgcn_mfma_f32_16x16x32_bf16(a0, w01, accA1, 0, 0, 0);
        accA0 = __builtin_amdgcn_mfma_f32_16x16x32_bf16(a1, w10, accA0, 0, 0, 0);
        accA1 = __builtin_amdgcn_mfma_f32_16x16x32_bf16(a1, w11, accA1, 0, 0, 0);
        accB0 = __builtin_amdgcn_mfma_f32_16x16x32_bf16(c0, w00, accB0, 0, 0, 0);
        accB1 = __builtin_amdgcn_mfma_f32_16x16x32_bf16(c0, w01, accB1, 0, 0, 0);
        accB0 = __builtin_amdgcn_mfma_f32_16x16x32_bf16(c1, w10, accB0, 0, 0, 0);
        accB1 = __builtin_amdgcn_mfma_f32_16x16x32_bf16(c1, w11, accB1, 0, 0, 0);

        if (s < kSeq - 1) {                          // write s+1 into other buffer
#pragma unroll
            for (int i = 0; i < 4; ++i) {
                int rm = 4 * w + i;
                As[(s + 1) & 1][rm * 64 + (l ^ (rm & 7))] = pf[i];
            }
        }
        __syncthreads();                             // s+1 staged & visible
    }

    // epilogue: two batches' outputs
#pragma unroll
    for (int bb = 0; bb < 2; ++bb) {
        int b = (bb == 0) ? b0 : b1;
        f32x4 v0 = (bb == 0) ? accA0 : accB0;
        f32x4 v1 = (bb == 0) ? accA1 : accB1;
        int R0 = b * kNUp + ntile * 16 + kg * 4;
#pragma unroll
        for (int r4 = 0; r4 < 4; ++r4) {
            size_t orow = (size_t)(R0 + r4) * kCout;
            out[orow + m]      = fmaxf(v0[r4] + bsv0, 0.f);
            out[orow + 16 + m] = fmaxf(v1[r4] + bsv1, 0.f);
        }
    }
}

extern "C" void kernel_launch(void* const* d_in, const int* in_sizes, int n_in,
                              void* d_out, int out_size, void* d_ws, size_t ws_size,
                              hipStream_t stream) {
    const float* x    = (const float*)d_in[0];
    const float* val  = (const float*)d_in[1];
    const float* W    = (const float*)d_in[2];
    const float* bias = (const float*)d_in[3];
    const int* row     = (const int*)d_in[4];
    const int* col     = (const int*)d_in[5];
    const int* indices = (const int*)d_in[6];
    float* out = (float*)d_out;

    char* wsb = (char*)d_ws;
    unsigned short* poolb = (unsigned short*)(wsb + kOffPool);
    unsigned short* wfrag = (unsigned short*)(wsb + kOffWfrag);
    int* cursor  = (int*)(wsb + kOffCur);
    uint2* bucket = (uint2*)(wsb + kOffBucket);

    zero_kernel<<<(kNUp + 255) / 256, 256, 0, stream>>>(cursor);

    constexpr int prep_blocks = kWFragN / 256 + (kE + 255) / 256;  // 72 + 331
    prep_kernel<<<prep_blocks, 256, 0, stream>>>(W, wfrag, row, col, val, cursor, bucket);

    pool_gather<<<kNUp / 16 * kB, 256, 0, stream>>>(x, cursor, bucket, poolb);

    gemm_mfma<<<kNTiles, 256, 0, stream>>>(poolb, wfrag, bias, indices, out);
}

// Round 19
// 74.049 us; speedup vs baseline: 1.0473x; 1.0473x over previous
//
#include <hip/hip_runtime.h>
#include <hip/hip_bf16.h>

// SpiralDeblock: B=8, N_IN=7056, N_UP=28224, SEQ=9, CIN=64, COUT=32
namespace {
constexpr int kB    = 8;
constexpr int kNIn  = 7056;
constexpr int kNUp  = 28224;
constexpr int kSeq  = 9;
constexpr int kCin  = 64;
constexpr int kCout = 32;
constexpr int kE    = 3 * kNUp;          // 84672
constexpr int kMRows = kB * kNUp;        // 225792
constexpr int kMTiles = kMRows / 16;     // 14112
constexpr int kTilesPerB = kNUp / 16;    // 1764
constexpr int kWFragN = 18 * 2 * 64 * 8; // 18432 bf16 values (36,864 B)
constexpr int kCap   = 24;               // bucket capacity
constexpr int kGemmGrid = 1768;          // 8 tiles/block; 1768 = 8*221 (swizzle-exact)

// ws layout (bytes), 16B-aligned. poolb layout: [b][r][c] (batch-sliced ->
// per-XCD L2 residency; r18 proved transposing this costs 8 us).
constexpr size_t kOffPool   = 0;                          // 28,901,376
constexpr size_t kOffWfrag  = 28901376;                   // 36,864
constexpr size_t kOffCur    = kOffWfrag + 36864;          // 112,896
constexpr size_t kOffBucket = kOffCur + 112896;           // N_UP*24*8 = 5,419,008
}

typedef __attribute__((ext_vector_type(8))) short short8;
typedef __attribute__((ext_vector_type(4))) float f32x4;

__device__ __forceinline__ unsigned short f32_to_bf16(float f) {  // RNE
    unsigned int u = __float_as_uint(f);
    u += 0x7fffu + ((u >> 16) & 1u);
    return (unsigned short)(u >> 16);
}

// --- zero cursor (graph-safe) ----------------------------------------------
__global__ __launch_bounds__(256) void zero_kernel(int* __restrict__ cursor) {
    int i = blockIdx.x * 256 + threadIdx.x;
    if (i < kNUp) cursor[i] = 0;
}

// --- merged prep: blocks [0,72) W->fragment transpose; rest bucket edges ----
__global__ __launch_bounds__(256) void prep_kernel(const float* __restrict__ W,
                                                   unsigned short* __restrict__ wfrag,
                                                   const int* __restrict__ row,
                                                   const int* __restrict__ col,
                                                   const float* __restrict__ val,
                                                   int* __restrict__ cursor,
                                                   uint2* __restrict__ bucket) {
    int bid = blockIdx.x;
    if (bid < kWFragN / 256) {
        int i  = bid * 256 + threadIdx.x;
        int j  = i & 7;
        int l  = (i >> 3) & 63;
        int ct = (i >> 9) & 1;
        int ks = i >> 10;                            // 0..17
        int k  = ks * 32 + (l >> 4) * 8 + j;
        int o  = ct * 16 + (l & 15);
        wfrag[i] = f32_to_bf16(W[k * kCout + o]);
    } else {
        int e = (bid - kWFragN / 256) * 256 + threadIdx.x;
        if (e >= kE) return;
        int r = row[e];
        int slot = atomicAdd(&cursor[r], 1);
        if ((unsigned)slot < (unsigned)kCap)
            bucket[(size_t)r * kCap + slot] = make_uint2((unsigned)col[e], __float_as_uint(val[e]));
    }
}

// --- pooled[b,r,c] = sum_{edges of r} x[b,col,c]*val, stored bf16 -----------
// b = blockIdx&7: batch<->XCD affinity (1.8 MB x-slice per XCD L2). 22.2 us (r10).
__global__ __launch_bounds__(256) void pool_gather(const float* __restrict__ x,
                                                   const int* __restrict__ cursor,
                                                   const uint2* __restrict__ bucket,
                                                   unsigned short* __restrict__ poolb) {
    int t  = threadIdx.x;
    int c4 = t & 15;
    int b  = blockIdx.x & 7;
    int rb = blockIdx.x >> 3;
    int r  = rb * 16 + (t >> 4);
    int n  = min(cursor[r], kCap);
    const uint2* bk = bucket + (size_t)r * kCap;
    const float* xb = x + (size_t)b * kNIn * kCin + (size_t)c4 * 4;

    f32x4 acc = {0.f, 0.f, 0.f, 0.f};
#pragma unroll
    for (int p = 0; p < 4; ++p) {
        if (2 * p < n) {
            uint4 q = *reinterpret_cast<const uint4*>(bk + 2 * p);
            unsigned c0 = min(q.x, (unsigned)(kNIn - 1));
            float    v0 = __uint_as_float(q.y);
            unsigned c1 = min(q.z, (unsigned)(kNIn - 1));
            float    v1 = (2 * p + 1 < n) ? __uint_as_float(q.w) : 0.f;
            f32x4 xv0 = *reinterpret_cast<const f32x4*>(xb + (size_t)c0 * kCin);
            f32x4 xv1 = *reinterpret_cast<const f32x4*>(xb + (size_t)c1 * kCin);
#pragma unroll
            for (int j = 0; j < 4; ++j)
                acc[j] = fmaf(xv1[j], v1, fmaf(xv0[j], v0, acc[j]));
        }
    }
    for (int k = 8; k < n; ++k) {                    // rare tail
        uint2 ev = bk[k];
        float v = __uint_as_float(ev.y);
        f32x4 xv = *reinterpret_cast<const f32x4*>(xb + (size_t)ev.x * kCin);
#pragma unroll
        for (int j = 0; j < 4; ++j) acc[j] = fmaf(xv[j], v, acc[j]);
    }
    ushort4 o;
    o.x = f32_to_bf16(acc[0]);
    o.y = f32_to_bf16(acc[1]);
    o.z = f32_to_bf16(acc[2]);
    o.w = f32_to_bf16(acc[3]);
    *reinterpret_cast<ushort4*>(poolb + ((size_t)b * kNUp + r) * kCin + c4 * 4) = o;
}

// --- MFMA GEMM (r17 config, best verified) + NT out-stores ------------------
// 8 waves/block (512 thr), one 16-row tile per wave, shared 36.9KB Bs fill,
// 32 waves/CU. Gather is at the scattered-segment throughput wall (r15-r18:
// ILP/MLP/occupancy/coalescing all null). NEW: out written with nontemporal
// stores -- 29MB streamed once, never re-read; keeps it from competing with
// the pooled slice in each XCD's L2.
__global__ __launch_bounds__(512, 8) void gemm_mfma(const unsigned short* __restrict__ poolb,
                                                    const unsigned short* __restrict__ wfrag,
                                                    const float* __restrict__ bias,
                                                    const int* __restrict__ indices,
                                                    float* __restrict__ out) {
    __shared__ short8 Bs[18 * 2 * 64];               // 2304 short8 = 36,864 B
    int t = threadIdx.x;
    const short8* wf = (const short8*)wfrag;
#pragma unroll
    for (int i = 0; i < 5; ++i) {                    // 2304 = 4*512 + 256
        int idx = i * 512 + t;
        if (idx < 18 * 2 * 64) Bs[idx] = wf[idx];
    }

    int l = t & 63;
    int w = t >> 6;                                  // wave 0..7
    int m  = l & 15;
    int kg = l >> 4;
    int bid = blockIdx.x;
    int wgid = (bid & 7) * 221 + (bid >> 3);         // grid 1768 = 8*221
    int mtile = wgid * 8 + w;
    bool active = (mtile < kMTiles);                 // wave-uniform guard
    if (active) {
        int b  = mtile / kTilesPerB;
        int nn = (mtile - b * kTilesPerB) * 16 + m;
        const unsigned short* pb = poolb + (size_t)b * kNUp * kCin;

        int idxs[kSeq];
#pragma unroll
        for (int s = 0; s < kSeq; ++s) idxs[s] = indices[nn * kSeq + s];

        float bs0 = bias[m];
        float bs1 = bias[16 + m];

        __syncthreads();                             // Bs ready

        f32x4 acc0 = {0.f, 0.f, 0.f, 0.f};
        f32x4 acc1 = {0.f, 0.f, 0.f, 0.f};
#pragma unroll
        for (int s = 0; s < kSeq; ++s) {
            const short8* ar = (const short8*)(pb + (size_t)idxs[s] * kCin);
            short8 a0 = ar[kg];                      // channels 0..31
            short8 a1 = ar[4 + kg];                  // channels 32..63
            short8 b00 = Bs[(4 * s + 0) * 64 + l];
            short8 b01 = Bs[(4 * s + 1) * 64 + l];
            short8 b10 = Bs[(4 * s + 2) * 64 + l];
            short8 b11 = Bs[(4 * s + 3) * 64 + l];
            acc0 = __builtin_amdgcn_mfma_f32_16x16x32_bf16(a0, b00, acc0, 0, 0, 0);
            acc1 = __builtin_amdgcn_mfma_f32_16x16x32_bf16(a0, b01, acc1, 0, 0, 0);
            acc0 = __builtin_amdgcn_mfma_f32_16x16x32_bf16(a1, b10, acc0, 0, 0, 0);
            acc1 = __builtin_amdgcn_mfma_f32_16x16x32_bf16(a1, b11, acc1, 0, 0, 0);
        }

        int orow0 = mtile * 16 + kg * 4;
#pragma unroll
        for (int r = 0; r < 4; ++r) {
            size_t orow = (size_t)(orow0 + r) * kCout;
            __builtin_nontemporal_store(fmaxf(acc0[r] + bs0, 0.f), &out[orow + m]);
            __builtin_nontemporal_store(fmaxf(acc1[r] + bs1, 0.f), &out[orow + 16 + m]);
        }
    } else {
        __syncthreads();                             // keep barrier uniform
    }
}

extern "C" void kernel_launch(void* const* d_in, const int* in_sizes, int n_in,
                              void* d_out, int out_size, void* d_ws, size_t ws_size,
                              hipStream_t stream) {
    const float* x    = (const float*)d_in[0];
    const float* val  = (const float*)d_in[1];
    const float* W    = (const float*)d_in[2];
    const float* bias = (const float*)d_in[3];
    const int* row     = (const int*)d_in[4];
    const int* col     = (const int*)d_in[5];
    const int* indices = (const int*)d_in[6];
    float* out = (float*)d_out;

    char* wsb = (char*)d_ws;
    unsigned short* poolb = (unsigned short*)(wsb + kOffPool);
    unsigned short* wfrag = (unsigned short*)(wsb + kOffWfrag);
    int* cursor  = (int*)(wsb + kOffCur);
    uint2* bucket = (uint2*)(wsb + kOffBucket);

    zero_kernel<<<(kNUp + 255) / 256, 256, 0, stream>>>(cursor);

    constexpr int prep_blocks = kWFragN / 256 + (kE + 255) / 256;  // 72 + 331
    prep_kernel<<<prep_blocks, 256, 0, stream>>>(W, wfrag, row, col, val, cursor, bucket);

    pool_gather<<<kNUp / 16 * kB, 256, 0, stream>>>(x, cursor, bucket, poolb);

    gemm_mfma<<<kGemmGrid, 512, 0, stream>>>(poolb, wfrag, bias, indices, out);
}